// Round 8
// baseline (251.073 us; speedup 1.0000x reference)
//
#include <hip/hip_runtime.h>
#include <hip/hip_bf16.h>
#include <math.h>

// (B,Cin,H,W)=(8,128,64,64), Cout=256, K=3, stride=1, pad=1, dil=1
#define B_    8
#define CIN   128
#define Hx    64
#define Wx    64
#define COUT  256
#define HW    4096
#define KTOT  1152      // CIN*9
#define NOFF  18
#define M_    32768     // B*HW
#define OFFSEG (B_ * NOFF * HW)   // 589824 floats per cin-segment partial
#define KCH   18        // K-chunks per half (chunk = 32 k)

typedef short bf16x8 __attribute__((ext_vector_type(8)));
typedef float f32x4  __attribute__((ext_vector_type(4)));

static __device__ __forceinline__ short f2bf(float f) {
  __hip_bfloat16 h = __float2bfloat16(f);
  return *reinterpret_cast<short*>(&h);
}

// ---------------- K1: offset conv ----------------
// block = (chalf 0..1, seg 0..7, r 0..63); thread -> (b,ho,wo-pair): 2 positions,
// 9 channels, 16 cins. Weight reads via float4 (ds_read_b128, 27/ci vs 81 b32);
// window columns shared between the 2 positions (12 loads serve 162 FMAs).
__global__ __launch_bounds__(256, 4) void offset_conv_kernel(
    const float* __restrict__ x, const float* __restrict__ ow,
    const float* __restrict__ ob, float* __restrict__ offp) {
  __shared__ __align__(16) float lds_w[16 * 9 * 12];   // [ci][ch][12 (9 taps + pad)]
  int blk = blockIdx.x;                     // 0..1023
  int r = blk & 63, seg = (blk >> 6) & 7, chalf = blk >> 9;
  int tid = threadIdx.x;
  for (int i = tid; i < 16 * 9 * 12; i += 256) {
    int t = i % 12;
    int rem = i / 12;                       // ci*9 + ch
    int ch = rem % 9, ci = rem / 9;
    lds_w[i] = (t < 9) ? ow[(chalf * 9 + ch) * KTOT + (seg * 16 + ci) * 9 + t] : 0.f;
  }
  __syncthreads();

  int v = r * 256 + tid;                    // 0..16383
  int wp = v & 31, ho = (v >> 5) & 63, b = v >> 11;
  int wo0 = wp * 2;
  float acc0[9], acc1[9];
#pragma unroll
  for (int c = 0; c < 9; ++c) { acc0[c] = 0.f; acc1[c] = 0.f; }
  const float* xb = x + (b * CIN + seg * 16) * HW;
  for (int ci = 0; ci < 16; ++ci) {
    const float* xp = xb + ci * HW;
    float win[3][4];
#pragma unroll
    for (int ky = 0; ky < 3; ++ky) {
      int iy = ho - 1 + ky;
      bool rok = (iy >= 0) & (iy < Hx);
      const float* rowp = xp + iy * Wx;
#pragma unroll
      for (int c = 0; c < 4; ++c) {
        int ix = wo0 - 1 + c;
        win[ky][c] = (rok & (ix >= 0) & (ix < Wx)) ? rowp[ix] : 0.f;
      }
    }
    const float4* wq = (const float4*)&lds_w[ci * 108];
#pragma unroll
    for (int ch = 0; ch < 9; ++ch) {
      float4 w0 = wq[ch * 3 + 0];           // taps 0..3
      float4 w1 = wq[ch * 3 + 1];           // taps 4..7
      float4 w2 = wq[ch * 3 + 2];           // tap 8
      float a0 = acc0[ch], a1 = acc1[ch];
      a0 = fmaf(win[0][0], w0.x, a0); a1 = fmaf(win[0][1], w0.x, a1);
      a0 = fmaf(win[0][1], w0.y, a0); a1 = fmaf(win[0][2], w0.y, a1);
      a0 = fmaf(win[0][2], w0.z, a0); a1 = fmaf(win[0][3], w0.z, a1);
      a0 = fmaf(win[1][0], w0.w, a0); a1 = fmaf(win[1][1], w0.w, a1);
      a0 = fmaf(win[1][1], w1.x, a0); a1 = fmaf(win[1][2], w1.x, a1);
      a0 = fmaf(win[1][2], w1.y, a0); a1 = fmaf(win[1][3], w1.y, a1);
      a0 = fmaf(win[2][0], w1.z, a0); a1 = fmaf(win[2][1], w1.z, a1);
      a0 = fmaf(win[2][1], w1.w, a0); a1 = fmaf(win[2][2], w1.w, a1);
      a0 = fmaf(win[2][2], w2.x, a0); a1 = fmaf(win[2][3], w2.x, a1);
      acc0[ch] = a0; acc1[ch] = a1;
    }
  }
  float* op = offp + seg * OFFSEG + (b * NOFF + chalf * 9) * HW + ho * 64 + wo0;
#pragma unroll
  for (int c = 0; c < 9; ++c) {
    float bias = (seg == 0) ? ob[chalf * 9 + c] : 0.f;
    op[c * HW]     = acc0[c] + bias;
    op[c * HW + 1] = acc1[c] + bias;
  }
}

// ---------------- K2: weight -> bf16 blocked Wb[kc][cout][32] (proven) ----------------
__global__ __launch_bounds__(256) void wt_cvt_kernel(
    const float* __restrict__ w, short* __restrict__ Wb) {
  int t = blockIdx.x * 256 + threadIdx.x;   // 294912
  int ki = t & 31;
  int cout = (t >> 5) & 255;
  int kc = t >> 13;                         // 0..35
  int k = kc * 32 + ki;
  int kk = k >> 7, cin = k & 127;
  Wb[t] = f2bf(w[(cout * CIN + cin) * 9 + kk]);
}

// ---------------- K3: bilinear coefficient tables (proven math, 8 partials) ----------------
__global__ __launch_bounds__(256) void coeff_kernel(
    const float* __restrict__ offp, short4* __restrict__ cidx, float4* __restrict__ cwt) {
  int t = blockIdx.x * 256 + threadIdx.x;   // 9*32768
  int m = t & (M_ - 1);
  int kk = t >> 15;                         // 0..8
  int b = m >> 12, ho = (m >> 6) & 63, wo = m & 63;
  int base = (b * NOFF + 2 * kk) * HW + (m & 4095);
  int base2 = base + HW;
  float dy = 0.f, dx = 0.f;
#pragma unroll
  for (int s = 0; s < 8; ++s) {
    dy += offp[base + s * OFFSEG];
    dx += offp[base2 + s * OFFSEG];
  }
  float sy = (float)(ho - 1 + kk / 3) + dy;
  float sx = (float)(wo - 1 + kk % 3) + dx;
  float fy = floorf(sy), fx = floorf(sx);
  int y0 = (int)fy, x0 = (int)fx;
  float wy = sy - fy, wx = sx - fx;
  int y1 = y0 + 1, x1 = x0 + 1;
  int cy0 = min(max(y0, 0), Hx - 1), cy1 = min(max(y1, 0), Hx - 1);
  int cx0 = min(max(x0, 0), Wx - 1), cx1 = min(max(x1, 0), Wx - 1);
  bool vy0 = (y0 >= 0) & (y0 < Hx), vy1 = (y1 >= 0) & (y1 < Hx);
  bool vx0 = (x0 >= 0) & (x0 < Wx), vx1 = (x1 >= 0) & (x1 < Wx);
  short4 id;
  id.x = (short)(cy0 * Wx + cx0); id.y = (short)(cy0 * Wx + cx1);
  id.z = (short)(cy1 * Wx + cx0); id.w = (short)(cy1 * Wx + cx1);
  float4 wv;
  wv.x = (vy0 && vx0) ? (1.f - wy) * (1.f - wx) : 0.f;
  wv.y = (vy0 && vx1) ? (1.f - wy) * wx : 0.f;
  wv.z = (vy1 && vx0) ? wy * (1.f - wx) : 0.f;
  wv.w = (vy1 && vx1) ? wy * wx : 0.f;
  cidx[t] = id;
  cwt[t] = wv;
}

// ---------------- K4: LDS-plane sampler, one K-half (verbatim round 7) ----------------
__global__ __launch_bounds__(256) void sampler_kernel(
    const float* __restrict__ x, const short4* __restrict__ cidx,
    const float4* __restrict__ cwt, short* __restrict__ Pb, int half) {
  __shared__ float lds_x[4 * HW];           // 65536 B
  int blk = blockIdx.x;
  int b = blk & 7;
  int g4 = blk >> 3;                        // 0..31
  int cinq = g4 >> 3;                       // chunk cin-quarter
  int e = g4 & 7;                           // 4-cin slot within chunk
  int tid = threadIdx.x;

  const float4* src = (const float4*)(x + (b * CIN + g4 * 4) * HW);
  float4* dst = (float4*)lds_x;
#pragma unroll
  for (int it = 0; it < 16; ++it)
    dst[it * 256 + tid] = src[it * 256 + tid];
  __syncthreads();

  for (int kk = 0; kk < 9; ++kk) {
    int kcg = kk * 4 + cinq;
    if ((kcg / KCH) != half) continue;      // block-uniform
    int kcl = kcg - half * KCH;
#pragma unroll
    for (int it = 0; it < 16; ++it) {
      int pos = it * 256 + tid;
      int m = b * HW + pos;
      short4 id = cidx[kk * M_ + m];
      float4 wv = cwt[kk * M_ + m];
      union { short s[4]; int2 v; } bu;
#pragma unroll
      for (int c = 0; c < 4; ++c) {
        const float* pl = lds_x + c * HW;
        float vsm = wv.x * pl[(int)id.x] + wv.y * pl[(int)id.y]
                  + wv.z * pl[(int)id.z] + wv.w * pl[(int)id.w];
        bu.s[c] = f2bf(vsm);
      }
      *(int2*)&Pb[((e * KCH + kcl) * M_ + m) * 4] = bu.v;
    }
  }
}

// ---------------- K5: bf16 MFMA GEMM, BK=64 (round-7 body, 2 sub-chunks/stage) ----------------
__global__ __launch_bounds__(256, 2) void gemm_kernel(
    const short* __restrict__ Wb, const short* __restrict__ Pb,
    float* __restrict__ y, int half) {
  __shared__ __align__(16) short sa[2][128 * 40];   // [sub][cout][k] pad 40
  __shared__ __align__(16) short sb[2][128 * 40];   // [sub][m][k]    pad 40

  int tid = threadIdx.x;
  int ct = blockIdx.x & 1;
  int mt = blockIdx.x >> 1;          // 0..255
  int cout0 = ct * 128;
  int m0 = mt * 128;

  int lane = tid & 63, wave = tid >> 6;
  int quad = lane >> 4, l16 = lane & 15;
  int wm = (wave & 1) << 6;          // cout sub-tile 0/64
  int wnm = (wave >> 1) << 6;        // m sub-tile 0/64

  int srow = tid >> 1;               // staging row 0..127
  int koff = (tid & 1) << 4;         // 0 or 16 shorts
  int e0 = koff >> 2;                // 0 or 4

  f32x4 zero = {0.f, 0.f, 0.f, 0.f};
  f32x4 acc[4][4];
#pragma unroll
  for (int i = 0; i < 4; ++i)
#pragma unroll
    for (int j = 0; j < 4; ++j) acc[i][j] = zero;

  for (int kp = 0; kp < 9; ++kp) {
    int4 aw[2][2];
    int2 bw[2][4];
#pragma unroll
    for (int sub = 0; sub < 2; ++sub) {
      int kcl = kp * 2 + sub;
      int kcg = half * KCH + kcl;
      const int4* asrc = (const int4*)&Wb[(kcg * 256 + cout0 + srow) * 32 + koff];
      aw[sub][0] = asrc[0];
      aw[sub][1] = asrc[1];
      int mrow = m0 + srow;
#pragma unroll
      for (int e = 0; e < 4; ++e)
        bw[sub][e] = *(const int2*)&Pb[((e0 + e) * KCH + kcl) * (M_ * 4) + mrow * 4];
    }
    __syncthreads();   // previous stage's frag reads done (WAR)
#pragma unroll
    for (int sub = 0; sub < 2; ++sub) {
      *(int4*)&sa[sub][srow * 40 + koff]      = aw[sub][0];
      *(int4*)&sa[sub][srow * 40 + koff + 8]  = aw[sub][1];
      *(int2*)&sb[sub][srow * 40 + koff]      = bw[sub][0];
      *(int2*)&sb[sub][srow * 40 + koff + 4]  = bw[sub][1];
      *(int2*)&sb[sub][srow * 40 + koff + 8]  = bw[sub][2];
      *(int2*)&sb[sub][srow * 40 + koff + 12] = bw[sub][3];
    }
    __syncthreads();   // tiles ready (RAW)

#pragma unroll
    for (int sub = 0; sub < 2; ++sub) {
      bf16x8 af[4], bfr[4];
#pragma unroll
      for (int i = 0; i < 4; ++i)
        af[i] = *(const bf16x8*)&sa[sub][(wm + i * 16 + l16) * 40 + quad * 8];
#pragma unroll
      for (int j = 0; j < 4; ++j)
        bfr[j] = *(const bf16x8*)&sb[sub][(wnm + j * 16 + l16) * 40 + quad * 8];
#pragma unroll
      for (int i = 0; i < 4; ++i)
#pragma unroll
        for (int j = 0; j < 4; ++j)
          acc[i][j] = __builtin_amdgcn_mfma_f32_16x16x32_bf16(af[i], bfr[j], acc[i][j], 0, 0, 0);
    }
  }

  // epilogue: y[(b,cout,ho,wo)]; half 0 writes, half 1 accumulates.
  // (dconv bias omitted: exactly cancelled by BN mean-subtraction)
#pragma unroll
  for (int i = 0; i < 4; ++i) {
    int crow = cout0 + wm + i * 16 + quad * 4;
#pragma unroll
    for (int j = 0; j < 4; ++j) {
      int m = m0 + wnm + j * 16 + l16;
      int b = m >> 12;
      float* yp = y + (b * COUT + crow) * HW + (m & 4095);
      if (half == 0) {
#pragma unroll
        for (int r2 = 0; r2 < 4; ++r2)
          yp[r2 * HW] = acc[i][j][r2];
      } else {
#pragma unroll
        for (int r2 = 0; r2 < 4; ++r2)
          yp[r2 * HW] += acc[i][j][r2];
      }
    }
  }
}

// ---------------- K6: BN batch stats (proven) ----------------
__global__ __launch_bounds__(256) void bn_stats_kernel(
    const float* __restrict__ y, float* __restrict__ mean, float* __restrict__ invstd) {
  int c = blockIdx.x;
  int tid = threadIdx.x;
  float s = 0.f, s2 = 0.f;
  for (int b = 0; b < B_; ++b) {
    const float4* p = (const float4*)(y + (b * COUT + c) * HW);
    for (int i = tid; i < HW / 4; i += 256) {
      float4 v = p[i];
      s += v.x + v.y + v.z + v.w;
      s2 = fmaf(v.x, v.x, s2); s2 = fmaf(v.y, v.y, s2);
      s2 = fmaf(v.z, v.z, s2); s2 = fmaf(v.w, v.w, s2);
    }
  }
#pragma unroll
  for (int o = 32; o > 0; o >>= 1) {
    s  += __shfl_down(s, o);
    s2 += __shfl_down(s2, o);
  }
  __shared__ float rs[4], rs2[4];
  int wid = tid >> 6, ln = tid & 63;
  if (ln == 0) { rs[wid] = s; rs2[wid] = s2; }
  __syncthreads();
  if (tid == 0) {
    float S  = rs[0] + rs[1] + rs[2] + rs[3];
    float S2 = rs2[0] + rs2[1] + rs2[2] + rs2[3];
    float m = S / 32768.f;
    float var = S2 / 32768.f - m * m;
    mean[c] = m;
    invstd[c] = rsqrtf(var + 1e-5f);
  }
}

// ---------------- K7: BN apply + SiLU, in place on y (= d_out) (proven) ----------------
__global__ __launch_bounds__(256) void bn_silu_kernel(
    float* __restrict__ y, const float* __restrict__ mean,
    const float* __restrict__ invstd, const float* __restrict__ gamma,
    const float* __restrict__ beta) {
  int i4 = blockIdx.x * 256 + threadIdx.x;   // 2097152 float4s
  int c = (i4 >> 10) & 255;
  float4 v = ((const float4*)y)[i4];
  float m = mean[c], sc = invstd[c] * gamma[c], bt = beta[c];
  float t0 = (v.x - m) * sc + bt;
  float t1 = (v.y - m) * sc + bt;
  float t2 = (v.z - m) * sc + bt;
  float t3 = (v.w - m) * sc + bt;
  float4 o;
  o.x = t0 / (1.f + expf(-t0));
  o.y = t1 / (1.f + expf(-t1));
  o.z = t2 / (1.f + expf(-t2));
  o.w = t3 / (1.f + expf(-t3));
  ((float4*)y)[i4] = o;
}

extern "C" void kernel_launch(void* const* d_in, const int* in_sizes, int n_in,
                              void* d_out, int out_size, void* d_ws, size_t ws_size,
                              hipStream_t stream) {
  const float* x     = (const float*)d_in[0];
  const float* ow    = (const float*)d_in[1];
  const float* ob    = (const float*)d_in[2];
  const float* dw    = (const float*)d_in[3];
  // d_in[4] = dconv bias: cancelled exactly by BN mean-subtraction
  const float* gamma = (const float*)d_in[5];
  const float* beta  = (const float*)d_in[6];
  float* y = (float*)d_out;                  // 8*256*4096 f32 — used as y buffer

  // ws layout (float offsets), total 16,073,216 floats = 64.3 MB
  float*  ws   = (float*)d_ws;
  short*  Pb   = (short*)ws;                 // 8e*18*32768*4 shorts = 9437184 floats
  float*  offp = ws + 9437184;               // 8 * 589824 = 4718592
  short4* cidx = (short4*)(ws + 14155776);   // 9*32768 short4 = 589824 floats
  float4* cwt  = (float4*)(ws + 14745600);   // 9*32768 float4 = 1179648 floats
  short*  Wb   = (short*)(ws + 15925248);    // 294912 shorts = 147456 floats
  float*  mean   = ws + 16072704;            // 256
  float*  invstd = ws + 16072960;            // 256

  offset_conv_kernel<<<1024, 256, 0, stream>>>(x, ow, ob, offp);
  wt_cvt_kernel<<<1152, 256, 0, stream>>>(dw, Wb);
  coeff_kernel<<<1152, 256, 0, stream>>>(offp, cidx, cwt);

  sampler_kernel<<<256, 256, 0, stream>>>(x, cidx, cwt, Pb, 0);
  gemm_kernel<<<512, 256, 0, stream>>>(Wb, Pb, y, 0);
  sampler_kernel<<<256, 256, 0, stream>>>(x, cidx, cwt, Pb, 1);
  gemm_kernel<<<512, 256, 0, stream>>>(Wb, Pb, y, 1);

  bn_stats_kernel<<<256, 256, 0, stream>>>(y, mean, invstd);
  bn_silu_kernel<<<8192, 256, 0, stream>>>(y, mean, invstd, gamma, beta);
}

// Round 9
// 233.739 us; speedup vs baseline: 1.0742x; 1.0742x over previous
//
#include <hip/hip_runtime.h>
#include <hip/hip_bf16.h>
#include <math.h>

// (B,Cin,H,W)=(8,128,64,64), Cout=256, K=3, stride=1, pad=1, dil=1
#define B_    8
#define CIN   128
#define Hx    64
#define Wx    64
#define COUT  256
#define HW    4096
#define KTOT  1152      // CIN*9
#define NOFF  18
#define M_    32768     // B*HW
#define OFFSEG (B_ * NOFF * HW)   // 589824 floats per cin-segment partial
#define NCH   36        // K-chunks (chunk = 32 k)

typedef short bf16x8 __attribute__((ext_vector_type(8)));
typedef float f32x4  __attribute__((ext_vector_type(4)));

typedef __attribute__((address_space(1))) const unsigned int gu32;
typedef __attribute__((address_space(3))) unsigned int lu32;
static __device__ __forceinline__ void async_cp16(const short* g, short* l) {
  __builtin_amdgcn_global_load_lds((gu32*)g, (lu32*)l, 16, 0, 0);
}

static __device__ __forceinline__ short f2bf(float f) {
  __hip_bfloat16 h = __float2bfloat16(f);
  return *reinterpret_cast<short*>(&h);
}

// ---------------- K1: offset conv (round-8 proven) ----------------
__global__ __launch_bounds__(256, 4) void offset_conv_kernel(
    const float* __restrict__ x, const float* __restrict__ ow,
    const float* __restrict__ ob, float* __restrict__ offp) {
  __shared__ __align__(16) float lds_w[16 * 9 * 12];   // [ci][ch][12 (9 taps + pad)]
  int blk = blockIdx.x;                     // 0..1023
  int r = blk & 63, seg = (blk >> 6) & 7, chalf = blk >> 9;
  int tid = threadIdx.x;
  for (int i = tid; i < 16 * 9 * 12; i += 256) {
    int t = i % 12;
    int rem = i / 12;                       // ci*9 + ch
    int ch = rem % 9, ci = rem / 9;
    lds_w[i] = (t < 9) ? ow[(chalf * 9 + ch) * KTOT + (seg * 16 + ci) * 9 + t] : 0.f;
  }
  __syncthreads();

  int v = r * 256 + tid;                    // 0..16383
  int wp = v & 31, ho = (v >> 5) & 63, b = v >> 11;
  int wo0 = wp * 2;
  float acc0[9], acc1[9];
#pragma unroll
  for (int c = 0; c < 9; ++c) { acc0[c] = 0.f; acc1[c] = 0.f; }
  const float* xb = x + (b * CIN + seg * 16) * HW;
  for (int ci = 0; ci < 16; ++ci) {
    const float* xp = xb + ci * HW;
    float win[3][4];
#pragma unroll
    for (int ky = 0; ky < 3; ++ky) {
      int iy = ho - 1 + ky;
      bool rok = (iy >= 0) & (iy < Hx);
      const float* rowp = xp + iy * Wx;
#pragma unroll
      for (int c = 0; c < 4; ++c) {
        int ix = wo0 - 1 + c;
        win[ky][c] = (rok & (ix >= 0) & (ix < Wx)) ? rowp[ix] : 0.f;
      }
    }
    const float4* wq = (const float4*)&lds_w[ci * 108];
#pragma unroll
    for (int ch = 0; ch < 9; ++ch) {
      float4 w0 = wq[ch * 3 + 0];
      float4 w1 = wq[ch * 3 + 1];
      float4 w2 = wq[ch * 3 + 2];
      float a0 = acc0[ch], a1 = acc1[ch];
      a0 = fmaf(win[0][0], w0.x, a0); a1 = fmaf(win[0][1], w0.x, a1);
      a0 = fmaf(win[0][1], w0.y, a0); a1 = fmaf(win[0][2], w0.y, a1);
      a0 = fmaf(win[0][2], w0.z, a0); a1 = fmaf(win[0][3], w0.z, a1);
      a0 = fmaf(win[1][0], w0.w, a0); a1 = fmaf(win[1][1], w0.w, a1);
      a0 = fmaf(win[1][1], w1.x, a0); a1 = fmaf(win[1][2], w1.x, a1);
      a0 = fmaf(win[1][2], w1.y, a0); a1 = fmaf(win[1][3], w1.y, a1);
      a0 = fmaf(win[2][0], w1.z, a0); a1 = fmaf(win[2][1], w1.z, a1);
      a0 = fmaf(win[2][1], w1.w, a0); a1 = fmaf(win[2][2], w1.w, a1);
      a0 = fmaf(win[2][2], w2.x, a0); a1 = fmaf(win[2][3], w2.x, a1);
      acc0[ch] = a0; acc1[ch] = a1;
    }
  }
  float* op = offp + seg * OFFSEG + (b * NOFF + chalf * 9) * HW + ho * 64 + wo0;
#pragma unroll
  for (int c = 0; c < 9; ++c) {
    float bias = (seg == 0) ? ob[chalf * 9 + c] : 0.f;
    op[c * HW]     = acc0[c] + bias;
    op[c * HW + 1] = acc1[c] + bias;
  }
}

// ---------------- K2: weight -> bf16 blocked Wb[kc][cout][32] (proven) ----------------
__global__ __launch_bounds__(256) void wt_cvt_kernel(
    const float* __restrict__ w, short* __restrict__ Wb) {
  int t = blockIdx.x * 256 + threadIdx.x;   // 294912
  int ki = t & 31;
  int cout = (t >> 5) & 255;
  int kc = t >> 13;                         // 0..35
  int k = kc * 32 + ki;
  int kk = k >> 7, cin = k & 127;
  Wb[t] = f2bf(w[(cout * CIN + cin) * 9 + kk]);
}

// ---------------- K3: bilinear coefficient tables (proven, 8 partials) ----------------
__global__ __launch_bounds__(256) void coeff_kernel(
    const float* __restrict__ offp, short4* __restrict__ cidx, float4* __restrict__ cwt) {
  int t = blockIdx.x * 256 + threadIdx.x;   // 9*32768
  int m = t & (M_ - 1);
  int kk = t >> 15;                         // 0..8
  int b = m >> 12, ho = (m >> 6) & 63, wo = m & 63;
  int base = (b * NOFF + 2 * kk) * HW + (m & 4095);
  int base2 = base + HW;
  float dy = 0.f, dx = 0.f;
#pragma unroll
  for (int s = 0; s < 8; ++s) {
    dy += offp[base + s * OFFSEG];
    dx += offp[base2 + s * OFFSEG];
  }
  float sy = (float)(ho - 1 + kk / 3) + dy;
  float sx = (float)(wo - 1 + kk % 3) + dx;
  float fy = floorf(sy), fx = floorf(sx);
  int y0 = (int)fy, x0 = (int)fx;
  float wy = sy - fy, wx = sx - fx;
  int y1 = y0 + 1, x1 = x0 + 1;
  int cy0 = min(max(y0, 0), Hx - 1), cy1 = min(max(y1, 0), Hx - 1);
  int cx0 = min(max(x0, 0), Wx - 1), cx1 = min(max(x1, 0), Wx - 1);
  bool vy0 = (y0 >= 0) & (y0 < Hx), vy1 = (y1 >= 0) & (y1 < Hx);
  bool vx0 = (x0 >= 0) & (x0 < Wx), vx1 = (x1 >= 0) & (x1 < Wx);
  short4 id;
  id.x = (short)(cy0 * Wx + cx0); id.y = (short)(cy0 * Wx + cx1);
  id.z = (short)(cy1 * Wx + cx0); id.w = (short)(cy1 * Wx + cx1);
  float4 wv;
  wv.x = (vy0 && vx0) ? (1.f - wy) * (1.f - wx) : 0.f;
  wv.y = (vy0 && vx1) ? (1.f - wy) * wx : 0.f;
  wv.z = (vy1 && vx0) ? wy * (1.f - wx) : 0.f;
  wv.w = (vy1 && vx1) ? wy * wx : 0.f;
  cidx[t] = id;
  cwt[t] = wv;
}

// ---------------- K4: LDS-plane sampler, full K, GEMM-friendly Pb layout ----------------
// blk = (khalf<<8)|(g4<<3)|b. Stages 4 x-planes (64 KB LDS), writes
// Pb[kcg][m][32] slot e (int2 at +e*4 shorts). khalf splits the kk loop for TLP.
__global__ __launch_bounds__(256) void sampler_kernel(
    const float* __restrict__ x, const short4* __restrict__ cidx,
    const float4* __restrict__ cwt, short* __restrict__ Pb) {
  __shared__ float lds_x[4 * HW];           // 65536 B
  int blk = blockIdx.x;                     // 0..511
  int b = blk & 7;
  int g4 = (blk >> 3) & 31;                 // 0..31
  int khalf = blk >> 8;
  int cinq = g4 >> 3;                       // cin-quarter within chunk group
  int e = g4 & 7;                           // 4-cin slot within chunk
  int tid = threadIdx.x;

  const float4* src = (const float4*)(x + (b * CIN + g4 * 4) * HW);
  float4* dst = (float4*)lds_x;
#pragma unroll
  for (int it = 0; it < 16; ++it)
    dst[it * 256 + tid] = src[it * 256 + tid];
  __syncthreads();

  int kk0 = khalf ? 5 : 0;
  int kk1 = khalf ? 9 : 5;
  for (int kk = kk0; kk < kk1; ++kk) {
    int kcg = kk * 4 + cinq;                // 0..35
#pragma unroll
    for (int it = 0; it < 16; ++it) {
      int pos = it * 256 + tid;
      int m = b * HW + pos;
      short4 id = cidx[kk * M_ + m];
      float4 wv = cwt[kk * M_ + m];
      union { short s[4]; int2 v; } bu;
#pragma unroll
      for (int c = 0; c < 4; ++c) {
        const float* pl = lds_x + c * HW;
        float vsm = wv.x * pl[(int)id.x] + wv.y * pl[(int)id.y]
                  + wv.z * pl[(int)id.z] + wv.w * pl[(int)id.w];
        bu.s[c] = f2bf(vsm);
      }
      *(int2*)&Pb[(kcg * M_ + m) * 32 + e * 4] = bu.v;
    }
  }
}

// ---------------- K5: single bf16 MFMA GEMM, m97-style async K-loop ----------------
// blk: mt = blk&255, ct = blk>>8 (ct-pair shares XCD -> Pb L2 reuse).
// Tile 128 cout x 128 m, K=1152 in 36 chunks of 32. Double-buffered 16KB LDS
// tiles staged by global_load_lds (flat 8KB A + 8KB B copies); ONE barrier per
// chunk; next chunk's DMA flies across the 16 MFMAs.
__global__ __launch_bounds__(256, 2) void gemm_kernel(
    const short* __restrict__ Wb, const short* __restrict__ Pb,
    float* __restrict__ y) {
  __shared__ __align__(16) short lds[2][8192];   // [buf][ A 4096 | B 4096 ] shorts

  int tid = threadIdx.x;
  int mt = blockIdx.x & 255;
  int ct = blockIdx.x >> 8;
  int cout0 = ct * 128;
  int m0 = mt * 128;

  int lane = tid & 63, wave = tid >> 6;
  int quad = lane >> 4, l16 = lane & 15;
  int wm = (wave & 1) << 6;          // cout sub-tile 0/64
  int wnm = (wave >> 1) << 6;        // m sub-tile 0/64

  // staging roles: waves 0,1 -> A halves; waves 2,3 -> B halves
  int isB = wave >> 1;
  int sub = wave & 1;
  const short* srcbase = isB ? (Pb + m0 * 32) : (Wb + cout0 * 32);
  const int sstride = isB ? (M_ * 32) : (256 * 32);
  const int soff = sub * 2048 + lane * 8;        // shorts
  const int doff = isB * 4096 + sub * 2048 + lane * 8;

  f32x4 zero = {0.f, 0.f, 0.f, 0.f};
  f32x4 acc[4][4];
#pragma unroll
  for (int i = 0; i < 4; ++i)
#pragma unroll
    for (int j = 0; j < 4; ++j) acc[i][j] = zero;

  // prologue: chunk 0 -> buf 0
  {
    const short* s = srcbase + soff;
    short* d = &lds[0][doff];
#pragma unroll
    for (int j = 0; j < 4; ++j)
      async_cp16(s + j * 512, d + j * 512);
  }

  for (int ch = 0; ch < NCH; ++ch) {
    int p = ch & 1;
    __syncthreads();                 // drains DMA -> buf p ready; frag reads of p^1 done
    if (ch < NCH - 1) {
      const short* s = srcbase + (ch + 1) * sstride + soff;
      short* d = &lds[p ^ 1][doff];
#pragma unroll
      for (int j = 0; j < 4; ++j)
        async_cp16(s + j * 512, d + j * 512);   // flies across the MFMAs below
    }
    const short* sa = &lds[p][0];
    const short* sb = &lds[p][4096];
    bf16x8 af[4], bfr[4];
#pragma unroll
    for (int i = 0; i < 4; ++i)
      af[i] = *(const bf16x8*)&sa[(wm + i * 16 + l16) * 32 + quad * 8];
#pragma unroll
    for (int j = 0; j < 4; ++j)
      bfr[j] = *(const bf16x8*)&sb[(wnm + j * 16 + l16) * 32 + quad * 8];
#pragma unroll
    for (int i = 0; i < 4; ++i)
#pragma unroll
      for (int j = 0; j < 4; ++j)
        acc[i][j] = __builtin_amdgcn_mfma_f32_16x16x32_bf16(af[i], bfr[j], acc[i][j], 0, 0, 0);
  }

  // epilogue: write y once (dconv bias cancels in BN mean-subtraction)
#pragma unroll
  for (int i = 0; i < 4; ++i) {
    int crow = cout0 + wm + i * 16 + quad * 4;
#pragma unroll
    for (int j = 0; j < 4; ++j) {
      int m = m0 + wnm + j * 16 + l16;
      int b = m >> 12;
      float* yp = y + (b * COUT + crow) * HW + (m & 4095);
#pragma unroll
      for (int r2 = 0; r2 < 4; ++r2)
        yp[r2 * HW] = acc[i][j][r2];
    }
  }
}

// ---------------- K6: BN batch stats (proven) ----------------
__global__ __launch_bounds__(256) void bn_stats_kernel(
    const float* __restrict__ y, float* __restrict__ mean, float* __restrict__ invstd) {
  int c = blockIdx.x;
  int tid = threadIdx.x;
  float s = 0.f, s2 = 0.f;
  for (int b = 0; b < B_; ++b) {
    const float4* p = (const float4*)(y + (b * COUT + c) * HW);
    for (int i = tid; i < HW / 4; i += 256) {
      float4 v = p[i];
      s += v.x + v.y + v.z + v.w;
      s2 = fmaf(v.x, v.x, s2); s2 = fmaf(v.y, v.y, s2);
      s2 = fmaf(v.z, v.z, s2); s2 = fmaf(v.w, v.w, s2);
    }
  }
#pragma unroll
  for (int o = 32; o > 0; o >>= 1) {
    s  += __shfl_down(s, o);
    s2 += __shfl_down(s2, o);
  }
  __shared__ float rs[4], rs2[4];
  int wid = tid >> 6, ln = tid & 63;
  if (ln == 0) { rs[wid] = s; rs2[wid] = s2; }
  __syncthreads();
  if (tid == 0) {
    float S  = rs[0] + rs[1] + rs[2] + rs[3];
    float S2 = rs2[0] + rs2[1] + rs2[2] + rs2[3];
    float m = S / 32768.f;
    float var = S2 / 32768.f - m * m;
    mean[c] = m;
    invstd[c] = rsqrtf(var + 1e-5f);
  }
}

// ---------------- K7: BN apply + SiLU, in place on y (= d_out) (proven) ----------------
__global__ __launch_bounds__(256) void bn_silu_kernel(
    float* __restrict__ y, const float* __restrict__ mean,
    const float* __restrict__ invstd, const float* __restrict__ gamma,
    const float* __restrict__ beta) {
  int i4 = blockIdx.x * 256 + threadIdx.x;   // 2097152 float4s
  int c = (i4 >> 10) & 255;
  float4 v = ((const float4*)y)[i4];
  float m = mean[c], sc = invstd[c] * gamma[c], bt = beta[c];
  float t0 = (v.x - m) * sc + bt;
  float t1 = (v.y - m) * sc + bt;
  float t2 = (v.z - m) * sc + bt;
  float t3 = (v.w - m) * sc + bt;
  float4 o;
  o.x = t0 / (1.f + expf(-t0));
  o.y = t1 / (1.f + expf(-t1));
  o.z = t2 / (1.f + expf(-t2));
  o.w = t3 / (1.f + expf(-t3));
  ((float4*)y)[i4] = o;
}

extern "C" void kernel_launch(void* const* d_in, const int* in_sizes, int n_in,
                              void* d_out, int out_size, void* d_ws, size_t ws_size,
                              hipStream_t stream) {
  const float* x     = (const float*)d_in[0];
  const float* ow    = (const float*)d_in[1];
  const float* ob    = (const float*)d_in[2];
  const float* dw    = (const float*)d_in[3];
  // d_in[4] = dconv bias: cancelled exactly by BN mean-subtraction
  const float* gamma = (const float*)d_in[5];
  const float* beta  = (const float*)d_in[6];
  float* y = (float*)d_out;                  // 8*256*4096 f32 — y buffer, finished in place

  // ws layout (float offsets), total 25,510,400 floats = 102.0 MB (ws = 256 MiB)
  float*  ws   = (float*)d_ws;
  short*  Pb   = (short*)ws;                 // 36*32768*32 shorts = 18874368 floats
  float*  offp = ws + 18874368;              // 8 * 589824 = 4718592
  short4* cidx = (short4*)(ws + 23592960);   // 9*32768 short4 = 589824 floats
  float4* cwt  = (float4*)(ws + 24182784);   // 9*32768 float4 = 1179648 floats
  short*  Wb   = (short*)(ws + 25362432);    // 294912 shorts = 147456 floats
  float*  mean   = ws + 25509888;            // 256
  float*  invstd = ws + 25510144;            // 256

  offset_conv_kernel<<<1024, 256, 0, stream>>>(x, ow, ob, offp);
  wt_cvt_kernel<<<1152, 256, 0, stream>>>(dw, Wb);
  coeff_kernel<<<1152, 256, 0, stream>>>(offp, cidx, cwt);
  sampler_kernel<<<512, 256, 0, stream>>>(x, cidx, cwt, Pb);
  gemm_kernel<<<512, 256, 0, stream>>>(Wb, Pb, y);
  bn_stats_kernel<<<256, 256, 0, stream>>>(y, mean, invstd);
  bn_silu_kernel<<<8192, 256, 0, stream>>>(y, mean, invstd, gamma, beta);
}